// Round 12
// baseline (159.854 us; speedup 1.0000x reference)
//
#include <hip/hip_runtime.h>

// HolographicBlock: B=2, S=2048, D=1024, R=64, H=8, HD=128
// Projections = bf16 MFMA GEMMs; fused up->down kernels.
// Attention = 640 uniform K-slices (<=8 tiles) + XCD-pinned bh pairs +
// 48KB LDS (3 blocks/CU) + exp2-domain static-offset softmax + bf16 partials.

#define Bn 2
#define Sn 2048
#define Dn 1024
#define Rn 64
#define Hn 8
#define HDn 128
#define Mn (Bn*Sn)   // 4096 rows
#define TSTRIDE ((size_t)Mn * Rn)

typedef __bf16 bf16x8 __attribute__((ext_vector_type(8)));
typedef float f32x4 __attribute__((ext_vector_type(4)));

__device__ __forceinline__ float bf2f(unsigned short u){
    union { unsigned int i; float f; } x; x.i = ((unsigned int)u) << 16; return x.f;
}
__device__ __forceinline__ unsigned short f2bf(float f){
    union { float f; unsigned int i; } x; x.f = f;
    unsigned int r = x.i + 0x7fffu + ((x.i >> 16) & 1u);
    return (unsigned short)(r >> 16);
}
__device__ __forceinline__ unsigned int pk2(float a, float b){
    unsigned int r;
    asm("v_cvt_pk_bf16_f32 %0, %1, %2" : "=v"(r) : "v"(a), "v"(b));
    return r;
}
__device__ __forceinline__ float vexp2(float x){
    float r;
    asm("v_exp_f32 %0, %1" : "=v"(r) : "v"(x));
    return r;
}

// ---------------- prep: bf16 transposed weights + rope table
__global__ __launch_bounds__(256) void prep_g(const float* __restrict__ A,
                                              const float* __restrict__ Bsrc,
                                              const float* __restrict__ Cq, const float* __restrict__ Ck,
                                              const float* __restrict__ Cv, const float* __restrict__ Co,
                                              const float* __restrict__ Cfc, const float* __restrict__ Cpr,
                                              const float* __restrict__ s1, const float* __restrict__ s2,
                                              unsigned short* __restrict__ At0, unsigned short* __restrict__ At1,
                                              unsigned short* __restrict__ At2,
                                              unsigned short* __restrict__ Btq, unsigned short* __restrict__ Btk,
                                              unsigned short* __restrict__ Btv, unsigned short* __restrict__ Bto,
                                              unsigned short* __restrict__ Btfc, unsigned short* __restrict__ Btpr,
                                              float2* __restrict__ rt){
    int idx = blockIdx.x * 256 + threadIdx.x;
    if (idx < 3 * 65536){
        int v = idx >> 16, e = idx & 65535;
        int r = e >> 10, d = e & 1023;
        float sc = (v == 0) ? 1.f : (v == 1 ? s1[d] : s2[d]);
        unsigned short val = f2bf(A[d * 64 + r] * sc);
        (v == 0 ? At0 : v == 1 ? At1 : At2)[e] = val;
    } else if (idx < 9 * 65536){
        int v = (idx - 3 * 65536) >> 16, e = idx & 65535;
        int d = e >> 6, r = e & 63;
        const float* C = v==0?Cq : v==1?Ck : v==2?Cv : v==3?Co : v==4?Cfc : Cpr;
        float extra = (v == 0) ? (0.08838834764831845f * 1.4426950408889634f) : 1.f;
        unsigned short val = f2bf(Bsrc[r * 1024 + d] * C[r] * extra);
        (v==0?Btq : v==1?Btk : v==2?Btv : v==3?Bto : v==4?Btfc : Btpr)[e] = val;
    } else if (idx < 9 * 65536 + Sn * 64){
        int e = idx - 9 * 65536;
        int s = e >> 6, f = e & 63;
        float inv = exp2f(-(float)f * (13.287712379549449f / 64.0f));
        float fr = (float)s * inv;
        float sn, cs; sincosf(fr, &sn, &cs);
        rt[e] = make_float2(cs, sn);
    }
}

// ---------------- down GEMM (K-split)
template<int IN_BF16, int WRITE_SS>
__global__ __launch_bounds__(256) void down_g(const void* __restrict__ inp,
                                              const unsigned short* __restrict__ At,
                                              float* __restrict__ tpart,
                                              float* __restrict__ sspart){
    __shared__ char xt[8192];
    __shared__ char at[8192];
    int tid = threadIdx.x;
    int m0 = blockIdx.x * 64, sp = blockIdx.y;
    int row = tid >> 2, q4 = tid & 3;
    int w = tid >> 6, lane = tid & 63, l4 = lane >> 4, lm = lane & 15;
    int swz = (row & 7) << 4;
    float ss = 0.f;
    f32x4 acc[4];
    #pragma unroll
    for (int nt = 0; nt < 4; ++nt) acc[nt] = (f32x4){0.f,0.f,0.f,0.f};

    float4 xr[4]; uint4 xrb[2]; uint4 ar[2];
    #define LOADC(c) { int k0 = sp * 256 + (c) * 64; \
        if (!IN_BF16){ const float4* s = (const float4*)((const float*)inp + (size_t)(m0+row)*1024 + k0 + q4*16); \
            xr[0]=s[0]; xr[1]=s[1]; xr[2]=s[2]; xr[3]=s[3]; } \
        else { const uint4* s = (const uint4*)((const unsigned short*)inp + (size_t)(m0+row)*1024 + k0 + q4*16); \
            xrb[0]=s[0]; xrb[1]=s[1]; } \
        const uint4* a = (const uint4*)(At + (size_t)row*1024 + k0 + q4*16); \
        ar[0]=a[0]; ar[1]=a[1]; }

    LOADC(0);
    for (int c = 0; c < 4; ++c){
        int b0 = row * 128 + ((q4 * 32) ^ swz);
        int b1 = row * 128 + ((q4 * 32 + 16) ^ swz);
        if (!IN_BF16){
            if (WRITE_SS){
                #pragma unroll
                for (int i = 0; i < 4; ++i)
                    ss += xr[i].x*xr[i].x + xr[i].y*xr[i].y + xr[i].z*xr[i].z + xr[i].w*xr[i].w;
            }
            uint4 p0 = {pk2(xr[0].x,xr[0].y), pk2(xr[0].z,xr[0].w), pk2(xr[1].x,xr[1].y), pk2(xr[1].z,xr[1].w)};
            uint4 p1 = {pk2(xr[2].x,xr[2].y), pk2(xr[2].z,xr[2].w), pk2(xr[3].x,xr[3].y), pk2(xr[3].z,xr[3].w)};
            *(uint4*)(xt + b0) = p0; *(uint4*)(xt + b1) = p1;
        } else {
            *(uint4*)(xt + b0) = xrb[0]; *(uint4*)(xt + b1) = xrb[1];
        }
        *(uint4*)(at + b0) = ar[0]; *(uint4*)(at + b1) = ar[1];
        __syncthreads();
        if (c < 3) LOADC(c + 1);
        #pragma unroll
        for (int ks = 0; ks < 2; ++ks){
            int arow = 16 * w + lm;
            bf16x8 af = *(const bf16x8*)(xt + arow * 128 + ((ks*64 + l4*16) ^ ((arow & 7) << 4)));
            #pragma unroll
            for (int nt = 0; nt < 4; ++nt){
                int brow = nt * 16 + lm;
                bf16x8 bf = *(const bf16x8*)(at + brow * 128 + ((ks*64 + l4*16) ^ ((brow & 7) << 4)));
                acc[nt] = __builtin_amdgcn_mfma_f32_16x16x32_bf16(af, bf, acc[nt], 0, 0, 0);
            }
        }
        __syncthreads();
    }
    #undef LOADC
    if (!IN_BF16 && WRITE_SS){
        ss += __shfl_xor(ss, 1); ss += __shfl_xor(ss, 2);
        if (q4 == 0) sspart[sp * Mn + m0 + row] = ss;
    }
    #pragma unroll
    for (int nt = 0; nt < 4; ++nt)
        #pragma unroll
        for (int r = 0; r < 4; ++r){
            int ml = 16 * w + 4 * l4 + r;
            tpart[(size_t)sp * TSTRIDE + (size_t)(m0 + ml) * 64 + nt * 16 + lm] = acc[nt][r];
        }
}

// ---------------- stage t tile (sum 4 K-split partials, optional rms scale)
template<int DORMS>
__device__ __forceinline__ void stage_t(char* tt, const float* __restrict__ tpart,
                                        const float* __restrict__ sspart, int m0, int tid){
    int row = tid >> 2, q4 = tid & 3;
    const float* bp = tpart + (size_t)(m0 + row) * 64 + q4 * 16;
    float4 s[4];
    #pragma unroll
    for (int i = 0; i < 4; ++i){
        float4 a = ((const float4*)(bp + 0 * TSTRIDE))[i];
        float4 b = ((const float4*)(bp + 1 * TSTRIDE))[i];
        float4 c = ((const float4*)(bp + 2 * TSTRIDE))[i];
        float4 d = ((const float4*)(bp + 3 * TSTRIDE))[i];
        s[i] = make_float4(a.x+b.x+c.x+d.x, a.y+b.y+c.y+d.y, a.z+b.z+c.z+d.z, a.w+b.w+c.w+d.w);
    }
    float rr = 1.f;
    if (DORMS){
        int m = m0 + row;
        float ssum = sspart[m] + sspart[Mn + m] + sspart[2*Mn + m] + sspart[3*Mn + m];
        rr = rsqrtf(ssum * (1.f / 1024.f) + 1.1920929e-07f);
    }
    #pragma unroll
    for (int i = 0; i < 4; ++i){ s[i].x*=rr; s[i].y*=rr; s[i].z*=rr; s[i].w*=rr; }
    int swz = (row & 7) << 4;
    uint4 p0 = {pk2(s[0].x,s[0].y), pk2(s[0].z,s[0].w), pk2(s[1].x,s[1].y), pk2(s[1].z,s[1].w)};
    uint4 p1 = {pk2(s[2].x,s[2].y), pk2(s[2].z,s[2].w), pk2(s[3].x,s[3].y), pk2(s[3].z,s[3].w)};
    *(uint4*)(tt + row * 128 + ((q4 * 32) ^ swz)) = p0;
    *(uint4*)(tt + row * 128 + ((q4 * 32 + 16) ^ swz)) = p1;
}

// ---------------- up GEMM (final projection only)
template<int SILU, int HASBASE, int OUT_BF16, int DORMS>
__global__ __launch_bounds__(256) void up_g(const float* __restrict__ tpart,
                                            const float* __restrict__ sspart,
                                            const unsigned short* __restrict__ Bt,
                                            const float* base,
                                            void* __restrict__ outp){
    __shared__ char tt[4096];
    __shared__ char bb[32768];
    int tid = threadIdx.x;
    int m0 = blockIdx.x * 32, n0 = blockIdx.y * 256;
    int w = tid >> 6, lane = tid & 63, l4 = lane >> 4, lm = lane & 15;
    int wm = w & 1, wn = w >> 1;
    if (tid < 128) stage_t<DORMS>(tt, tpart, sspart, m0, tid);
    {
        const uint4* s = (const uint4*)(Bt + (size_t)(n0 + tid) * 64);
        #pragma unroll
        for (int j = 0; j < 8; ++j){
            uint4 v = s[j];
            *(uint4*)(bb + tid * 128 + ((j * 16) ^ ((tid & 7) << 4))) = v;
        }
    }
    __syncthreads();
    bf16x8 af[2];
    #pragma unroll
    for (int ks = 0; ks < 2; ++ks){
        int arow = 16 * wm + lm;
        af[ks] = *(const bf16x8*)(tt + arow * 128 + ((ks*64 + l4*16) ^ ((arow & 7) << 4)));
    }
    f32x4 acc[8];
    #pragma unroll
    for (int nt = 0; nt < 8; ++nt) acc[nt] = (f32x4){0.f,0.f,0.f,0.f};
    #pragma unroll
    for (int nt = 0; nt < 8; ++nt){
        int brow = wn * 128 + nt * 16 + lm;
        #pragma unroll
        for (int ks = 0; ks < 2; ++ks){
            bf16x8 bf = *(const bf16x8*)(bb + brow * 128 + ((ks*64 + l4*16) ^ ((brow & 7) << 4)));
            acc[nt] = __builtin_amdgcn_mfma_f32_16x16x32_bf16(af[ks], bf, acc[nt], 0, 0, 0);
        }
    }
    #pragma unroll
    for (int nt = 0; nt < 8; ++nt)
        #pragma unroll
        for (int r = 0; r < 4; ++r){
            int m = m0 + 16 * wm + 4 * l4 + r;
            int n = n0 + wn * 128 + nt * 16 + lm;
            float v = acc[nt][r];
            if (SILU) v = v / (1.f + __expf(-v));
            if (HASBASE) v += base[(size_t)m * 1024 + n];
            if (OUT_BF16) ((unsigned short*)outp)[(size_t)m * 1024 + n] = f2bf(v);
            else          ((float*)outp)[(size_t)m * 1024 + n] = v;
        }
}

// ---------------- FUSED up->down
template<int SILU, int HASBASE, int STOREOUT, int SUMSQ, int DORMS_IN>
__global__ __launch_bounds__(256) void updown_g(const float* __restrict__ tpin,
                                                const float* __restrict__ sspin,
                                                const unsigned short* __restrict__ BtU,
                                                const unsigned short* __restrict__ AtD,
                                                const float* base,
                                                float* outp,
                                                float* __restrict__ tpout,
                                                float* __restrict__ sspout){
    __shared__ char tt[4096];
    __shared__ char bb[32768];
    __shared__ char xb[16384];
    __shared__ float ssl[2][32];
    int tid = threadIdx.x;
    int m0 = blockIdx.x * 32, n0 = blockIdx.y * 256, sp = blockIdx.y;
    int w = tid >> 6, lane = tid & 63, l4 = lane >> 4, lm = lane & 15;
    int wm = w & 1, wn = w >> 1;
    if (tid < 128) stage_t<DORMS_IN>(tt, tpin, sspin, m0, tid);
    {
        const uint4* s = (const uint4*)(BtU + (size_t)(n0 + tid) * 64);
        #pragma unroll
        for (int j = 0; j < 8; ++j){
            uint4 v = s[j];
            *(uint4*)(bb + tid * 128 + ((j * 16) ^ ((tid & 7) << 4))) = v;
        }
    }
    __syncthreads();
    bf16x8 af[2];
    #pragma unroll
    for (int ks = 0; ks < 2; ++ks){
        int arow = 16 * wm + lm;
        af[ks] = *(const bf16x8*)(tt + arow * 128 + ((ks*64 + l4*16) ^ ((arow & 7) << 4)));
    }
    f32x4 acc[8];
    #pragma unroll
    for (int nt = 0; nt < 8; ++nt) acc[nt] = (f32x4){0.f,0.f,0.f,0.f};
    #pragma unroll
    for (int nt = 0; nt < 8; ++nt){
        int brow = wn * 128 + nt * 16 + lm;
        #pragma unroll
        for (int ks = 0; ks < 2; ++ks){
            bf16x8 bf = *(const bf16x8*)(bb + brow * 128 + ((ks*64 + l4*16) ^ ((brow & 7) << 4)));
            acc[nt] = __builtin_amdgcn_mfma_f32_16x16x32_bf16(af[ks], bf, acc[nt], 0, 0, 0);
        }
    }
    float val[8][4];
    float sq[4] = {0.f, 0.f, 0.f, 0.f};
    #pragma unroll
    for (int nt = 0; nt < 8; ++nt)
        #pragma unroll
        for (int r = 0; r < 4; ++r){
            int m = m0 + 16 * wm + 4 * l4 + r;
            int n = n0 + wn * 128 + nt * 16 + lm;
            float v = acc[nt][r];
            if (SILU) v = v / (1.f + __expf(-v));
            if (HASBASE) v += base[(size_t)m * 1024 + n];
            val[nt][r] = v;
            if (STOREOUT) outp[(size_t)m * 1024 + n] = v;
            if (SUMSQ) sq[r] += v * v;
        }
    if (SUMSQ){
        #pragma unroll
        for (int r = 0; r < 4; ++r){
            float s_ = sq[r];
            s_ += __shfl_xor(s_, 1);
            s_ += __shfl_xor(s_, 2);
            s_ += __shfl_xor(s_, 4);
            s_ += __shfl_xor(s_, 8);
            if (lm == 0) ssl[wn][16 * wm + 4 * l4 + r] = s_;
        }
    }
    __syncthreads();
    {
        int row = tid >> 2, q4 = tid & 3;
        const uint4* s = (const uint4*)(AtD + (size_t)row * 1024 + n0 + q4 * 64);
        #pragma unroll
        for (int j = 0; j < 8; ++j){
            uint4 v = s[j];
            int u = q4 * 8 + j;
            *(uint4*)(bb + row * 512 + ((u * 16) ^ ((row & 7) << 4))) = v;
        }
    }
    #pragma unroll
    for (int nt = 0; nt < 8; ++nt)
        #pragma unroll
        for (int r = 0; r < 4; ++r){
            int mrow = 16 * wm + 4 * l4 + r;
            int cn = wn * 128 + nt * 16 + lm;
            *(unsigned short*)(xb + mrow * 512 + ((cn * 2) ^ ((mrow & 7) << 4))) = f2bf(val[nt][r]);
        }
    __syncthreads();
    if (SUMSQ && tid < 32)
        sspout[sp * Mn + m0 + tid] = ssl[0][tid] + ssl[1][tid];
    f32x4 acc2[2];
    acc2[0] = (f32x4){0.f,0.f,0.f,0.f};
    acc2[1] = (f32x4){0.f,0.f,0.f,0.f};
    #pragma unroll
    for (int kk = 0; kk < 8; ++kk){
        int arow = 16 * (w & 1) + lm;
        bf16x8 a2 = *(const bf16x8*)(xb + arow * 512 + ((kk * 64 + l4 * 16) ^ ((arow & 7) << 4)));
        #pragma unroll
        for (int j = 0; j < 2; ++j){
            int brow = (2 * (w >> 1) + j) * 16 + lm;
            bf16x8 b2 = *(const bf16x8*)(bb + brow * 512 + ((kk * 64 + l4 * 16) ^ ((brow & 7) << 4)));
            acc2[j] = __builtin_amdgcn_mfma_f32_16x16x32_bf16(a2, b2, acc2[j], 0, 0, 0);
        }
    }
    #pragma unroll
    for (int j = 0; j < 2; ++j)
        #pragma unroll
        for (int r = 0; r < 4; ++r){
            int ml = 16 * (w & 1) + 4 * l4 + r;
            int nc = (2 * (w >> 1) + j) * 16 + lm;
            tpout[(size_t)sp * TSTRIDE + (size_t)(m0 + ml) * 64 + nc] = acc2[j][r];
        }
}

// ---------------- fused QKV up-proj + RoPE; K,V pre-swizzled tile images
__global__ __launch_bounds__(256) void qkv_g(const float* __restrict__ tpart,
                                             const float* __restrict__ sspart,
                                             const unsigned short* __restrict__ Btq,
                                             const unsigned short* __restrict__ Btk,
                                             const unsigned short* __restrict__ Btv,
                                             const float2* __restrict__ rt,
                                             unsigned short* __restrict__ qout,
                                             char* __restrict__ Kimg,
                                             char* __restrict__ Vimg){
    __shared__ char tt[8192];
    __shared__ char bb[32768];
    int tid = threadIdx.x;
    int m0 = blockIdx.x * 64, n0 = blockIdx.y * 256;
    int b = m0 >> 11, s0 = m0 & (Sn - 1);
    int h0 = n0 >> 7;
    int w = tid >> 6, lane = tid & 63, l4 = lane >> 4, lm = lane & 15;
    stage_t<1>(tt, tpart, sspart, m0, tid);
    #define STAGE_B(SRC) { const uint4* s = (const uint4*)((SRC) + (size_t)(n0 + tid) * 64); \
        _Pragma("unroll") for (int j = 0; j < 8; ++j){ uint4 v = s[j]; \
            *(uint4*)(bb + tid * 128 + ((j * 16) ^ ((tid & 7) << 4))) = v; } }
    STAGE_B(Btq);
    __syncthreads();
    bf16x8 af[2];
    #pragma unroll
    for (int ks = 0; ks < 2; ++ks){
        int arow = 16 * w + lm;
        af[ks] = *(const bf16x8*)(tt + arow * 128 + ((ks*64 + l4*16) ^ ((arow & 7) << 4)));
    }
    f32x4 acc[16];
    float2 cs[4][4];
    #pragma unroll
    for (int ntb = 0; ntb < 4; ++ntb)
        #pragma unroll
        for (int r = 0; r < 4; ++r)
            cs[ntb][r] = rt[(size_t)(s0 + 16*w + 4*l4 + r) * 64 + ntb * 16 + lm];

    #define MMUL() { _Pragma("unroll") for (int nt = 0; nt < 16; ++nt) acc[nt] = (f32x4){0.f,0.f,0.f,0.f}; \
        _Pragma("unroll") for (int nt = 0; nt < 16; ++nt){ int brow = nt * 16 + lm; \
            _Pragma("unroll") for (int ks = 0; ks < 2; ++ks){ \
                bf16x8 bf = *(const bf16x8*)(bb + brow * 128 + ((ks*64 + l4*16) ^ ((brow & 7) << 4))); \
                acc[nt] = __builtin_amdgcn_mfma_f32_16x16x32_bf16(af[ks], bf, acc[nt], 0, 0, 0); } } }

    #define ROPE() { _Pragma("unroll") for (int g = 0; g < 2; ++g) \
        _Pragma("unroll") for (int ntb = 0; ntb < 4; ++ntb){ int lo = g*8 + ntb, hi = lo + 4; \
            _Pragma("unroll") for (int r = 0; r < 4; ++r){ float2 c = cs[ntb][r]; \
                float a = acc[lo][r], bq = acc[hi][r]; \
                acc[lo][r] = a * c.x + bq * c.y; acc[hi][r] = -a * c.y + bq * c.x; } } }

    #define BOUNCE() { \
        _Pragma("unroll") for (int nt = 0; nt < 16; ++nt) \
            _Pragma("unroll") for (int r = 0; r < 4; ++r){ \
                int nl = nt * 16 + lm, ml2 = 16 * w + 4 * l4 + r; \
                *(unsigned short*)(bb + ml2 * 512 + ((nl * 2) ^ ((ml2 & 7) << 4))) = f2bf(acc[nt][r]); } \
        __syncthreads(); }

    MMUL(); ROPE();
    __syncthreads();
    BOUNCE();
    {
        int ml = tid >> 2, seg = tid & 3;
        int head = h0 + (seg >> 1), hd0q = (seg & 1) * 64;
        size_t dstbase = (((size_t)(b * 8 + head) * Sn + (s0 + ml)) * 128 + hd0q);
        #pragma unroll
        for (int j = 0; j < 8; ++j){
            uint4 v = *(const uint4*)(bb + ml * 512 + ((seg * 128 + j * 16) ^ ((ml & 7) << 4)));
            *(uint4*)(qout + dstbase + j * 8) = v;
        }
    }
    __syncthreads();
    STAGE_B(Btk);
    __syncthreads();
    MMUL(); ROPE();
    __syncthreads();
    BOUNCE();
    {
        int ml = tid >> 2, seg = tid & 3;
        int hd0q = (seg & 1) * 64;
        int head = h0 + (seg >> 1);
        int pr = 16 * (ml & 3) + (ml >> 2);
        size_t rowb = (((size_t)(b * 8 + head) * 32 + (s0 >> 6)) * 64 + pr) * 256;
        #pragma unroll
        for (int j = 0; j < 8; ++j){
            uint4 v = *(const uint4*)(bb + ml * 512 + ((seg * 128 + j * 16) ^ ((ml & 7) << 4)));
            int cb = hd0q * 2 + j * 16;
            *(uint4*)(Kimg + rowb + (cb ^ ((pr & 7) << 4))) = v;
        }
    }
    __syncthreads();
    STAGE_B(Btv);
    __syncthreads();
    MMUL();
    __syncthreads();
    #pragma unroll
    for (int nt = 0; nt < 16; ++nt)
        #pragma unroll
        for (int r = 0; r < 4; ++r){
            int nl = nt * 16 + lm, ml2 = 16 * w + 4 * l4 + r;
            *(unsigned short*)(bb + nl * 128 + ((ml2 * 2) ^ ((nl & 7) << 4))) = f2bf(acc[nt][r]);
        }
    __syncthreads();
    {
        int head = h0 + (tid >> 7), d = tid & 127;
        size_t rowb = (((size_t)(b * 8 + head) * 32 + (s0 >> 6)) * 128 + d) * 128;
        #pragma unroll
        for (int j = 0; j < 8; ++j){
            uint4 v = *(const uint4*)(bb + tid * 128 + ((j * 16) ^ ((tid & 7) << 4)));
            *(uint4*)(Vimg + rowb + ((j * 16) ^ ((d & 7) << 4))) = v;
        }
    }
    #undef STAGE_B
    #undef MMUL
    #undef ROPE
    #undef BOUNCE
}

// ---------------- K-sliced flash attention: 640 blocks, XCD-pinned bh pairs,
// 48KB LDS single buffer + reg-prefetch, exp2-domain static-offset softmax.
__global__ __launch_bounds__(256, 3) void attn2_kernel(const unsigned short* __restrict__ qb,
                                                       const char* __restrict__ Kimg,
                                                       const char* __restrict__ Vimg,
                                                       unsigned short* __restrict__ ybf,
                                                       unsigned short* __restrict__ pab,
                                                       float* __restrict__ pl){
    __shared__ uint4 smem4[49152 / 16];
    char* smem = (char*)smem4;
    int tid = threadIdx.x;
    int w = tid >> 6, lane = tid & 63, l4 = lane >> 4, lm = lane & 15;
    // XCD pinning: i&7 -> XCD; each XCD owns bh pair {2xg, 2xg+1}, 80 blocks
    int i = blockIdx.x;
    int xg = i & 7, u = i >> 3;          // u in [0,80)
    int bh = 2 * xg + (u & 1);
    int su = u >> 1;                     // 0..39
    int j, s;
    if (su < 4){ j = su; s = 0; }
    else if (su < 12){ j = 4 + ((su - 4) >> 1); s = (su - 4) & 1; }
    else if (su < 24){ j = 8 + (su - 12) / 3; s = (su - 12) % 3; }
    else { j = 12 + ((su - 24) >> 2); s = (su - 24) & 3; }
    int t0 = 8 * s;
    int tend = min(8 * s + 8, 2 * j + 2);
    int niters = tend - t0;
    int direct = (j < 4);
    int gslice = 0;
    if (!direct){
        int soff = (j < 8) ? (j - 4) * 2 : (j < 12) ? 8 + (j - 8) * 3 : 20 + (j - 12) * 4;
        gslice = bh * 36 + soff + s;
    }
    int b = bh >> 3, h = bh & 7;
    int qrow0w = 128 * j + 32 * w;
    int wqmax = qrow0w + 31;

    bf16x8 qf[2][4];
    #pragma unroll
    for (int f = 0; f < 2; ++f){
        const unsigned short* qg = qb + ((size_t)bh * Sn + qrow0w + 16 * f + lm) * HDn;
        #pragma unroll
        for (int df = 0; df < 4; ++df)
            qf[f][df] = *(const bf16x8*)(qg + df * 32 + l4 * 8);
    }
    f32x4 acc[2][8];
    #pragma unroll
    for (int f = 0; f < 2; ++f)
        #pragma unroll
        for (int dg = 0; dg < 8; ++dg) acc[f][dg] = (f32x4){0.f,0.f,0.f,0.f};
    float lp[2][4];
    #pragma unroll
    for (int f = 0; f < 2; ++f)
        #pragma unroll
        for (int r = 0; r < 4; ++r) lp[f][r] = 0.f;

    const float OFF = 11.541560327111708f;   // 8 * log2(e)
    size_t imgbase = (size_t)bh * 32 * 16384;
    char* KL = smem;
    char* VL = smem + 16384;
    char* pb = smem + 32768 + (w << 12);

    uint4 sk[4], sv4[4];
    {
        size_t tb = imgbase + (size_t)t0 * 16384;
        #pragma unroll
        for (int i2 = 0; i2 < 4; ++i2){
            sk[i2]  = *(const uint4*)(Kimg + tb + i2 * 4096 + tid * 16);
            sv4[i2] = *(const uint4*)(Vimg + tb + i2 * 4096 + tid * 16);
        }
        #pragma unroll
        for (int i2 = 0; i2 < 4; ++i2){
            *(uint4*)(KL + i2 * 4096 + tid * 16) = sk[i2];
            *(uint4*)(VL + i2 * 4096 + tid * 16) = sv4[i2];
        }
    }
    __syncthreads();

    for (int it = 0; it < niters; ++it){
        int t = t0 + it;
        if (it + 1 < niters){
            size_t tb = imgbase + (size_t)(t + 1) * 16384;
            #pragma unroll
            for (int i2 = 0; i2 < 4; ++i2){
                sk[i2]  = *(const uint4*)(Kimg + tb + i2 * 4096 + tid * 16);
                sv4[i2] = *(const uint4*)(Vimg + tb + i2 * 4096 + tid * 16);
            }
        }
        if (64 * t <= wqmax){
            __builtin_amdgcn_s_setprio(1);
            f32x4 sf[2][4];
            #pragma unroll
            for (int kc = 0; kc < 4; ++kc){ sf[0][kc] = (f32x4){0.f,0.f,0.f,0.f}; sf[1][kc] = (f32x4){0.f,0.f,0.f,0.f}; }
            #pragma unroll
            for (int kc = 0; kc < 4; ++kc){
                int krow = 16 * kc + lm;
                int ksw = (krow & 7) << 4;
                #pragma unroll
                for (int df = 0; df < 4; ++df){
                    bf16x8 kf = *(const bf16x8*)(KL + krow * 256 + ((df * 64 + l4 * 16) ^ ksw));
                    sf[0][kc] = __builtin_amdgcn_mfma_f32_16x16x32_bf16(qf[0][df], kf, sf[0][kc], 0, 0, 0);
                    sf[1][kc] = __builtin_amdgcn_mfma_f32_16x16x32_bf16(qf[1][df], kf, sf[1][kc], 0, 0, 0);
                }
            }
            // lane's score sf[kc][r] is for TRUE key 64t + 4*lm + kc (permuted image)
            bool needmask = (64 * t + 63 > qrow0w);
            #pragma unroll
            for (int f = 0; f < 2; ++f){
                #pragma unroll
                for (int r = 0; r < 4; ++r){
                    float s0v = sf[f][0][r], s1v = sf[f][1][r],
                          s2v = sf[f][2][r], s3v = sf[f][3][r];
                    if (needmask){
                        int qr = qrow0w + 16 * f + 4 * l4 + r;
                        int j0k = 64 * t + 4 * lm;
                        s0v = (j0k     > qr) ? -1e30f : s0v;
                        s1v = (j0k + 1 > qr) ? -1e30f : s1v;
                        s2v = (j0k + 2 > qr) ? -1e30f : s2v;
                        s3v = (j0k + 3 > qr) ? -1e30f : s3v;
                    }
                    float p0 = vexp2(s0v - OFF), p1 = vexp2(s1v - OFF),
                          p2 = vexp2(s2v - OFF), p3 = vexp2(s3v - OFF);
                    lp[f][r] += p0 + p1 + p2 + p3;
                    int prow = 16 * f + 4 * l4 + r;
                    uint2 pkd = {pk2(p0, p1), pk2(p2, p3)};
                    *(uint2*)(pb + prow * 128 + ((lm * 8) ^ ((prow & 7) << 4))) = pkd;
                }
            }
            #pragma unroll
            for (int ks = 0; ks < 2; ++ks){
                int pcol = (ks * 64 + l4 * 16) ^ ((lm & 7) << 4);
                bf16x8 pa0 = *(const bf16x8*)(pb + lm * 128 + pcol);
                bf16x8 pa1 = *(const bf16x8*)(pb + (16 + lm) * 128 + pcol);
                #pragma unroll
                for (int dg = 0; dg < 8; ++dg){
                    int vrow = 16 * dg + lm;
                    bf16x8 vf = *(const bf16x8*)(VL + vrow * 128 + ((ks * 64 + l4 * 16) ^ ((vrow & 7) << 4)));
                    acc[0][dg] = __builtin_amdgcn_mfma_f32_16x16x32_bf16(pa0, vf, acc[0][dg], 0, 0, 0);
                    acc[1][dg] = __builtin_amdgcn_mfma_f32_16x16x32_bf16(pa1, vf, acc[1][dg], 0, 0, 0);
                }
            }
            __builtin_amdgcn_s_setprio(0);
        }
        __syncthreads();
        if (it + 1 < niters){
            #pragma unroll
            for (int i2 = 0; i2 < 4; ++i2){
                *(uint4*)(KL + i2 * 4096 + tid * 16) = sk[i2];
                *(uint4*)(VL + i2 * 4096 + tid * 16) = sv4[i2];
            }
        }
        __syncthreads();
    }
    // epilogue: one cross-lane reduce of l per row
    float lsum[2][4];
    #pragma unroll
    for (int f = 0; f < 2; ++f)
        #pragma unroll
        for (int r = 0; r < 4; ++r){
            float l_ = lp[f][r];
            l_ += __shfl_xor(l_, 1);
            l_ += __shfl_xor(l_, 2);
            l_ += __shfl_xor(l_, 4);
            l_ += __shfl_xor(l_, 8);
            lsum[f][r] = l_;
        }
    if (direct){
        #pragma unroll
        for (int f = 0; f < 2; ++f)
            #pragma unroll
            for (int r = 0; r < 4; ++r){
                float inv = 1.f / lsum[f][r];
                int row = qrow0w + 16 * f + 4 * l4 + r;
                unsigned short* yr = ybf + ((size_t)b * Sn + row) * Dn + h * HDn;
                #pragma unroll
                for (int dg = 0; dg < 8; ++dg)
                    yr[16 * dg + lm] = f2bf(acc[f][dg][r] * inv);
            }
    } else {
        unsigned short* pa_ = pab + (size_t)gslice * 16384;
        #pragma unroll
        for (int f = 0; f < 2; ++f)
            #pragma unroll
            for (int r = 0; r < 4; ++r){
                int row = 32 * w + 16 * f + 4 * l4 + r;
                #pragma unroll
                for (int dg = 0; dg < 8; ++dg)
                    pa_[row * 128 + 16 * dg + lm] = f2bf(acc[f][dg][r]);
                if (lm == 0)
                    pl[gslice * 128 + row] = lsum[f][r];
            }
    }
}

// ---------------- combine 2-4 K-slices -> y (bf16): O = (ΣA)/(Σl)
__global__ __launch_bounds__(256) void comb_g(const unsigned short* __restrict__ pab,
                                              const float* __restrict__ pl,
                                              unsigned short* __restrict__ ybf){
    int bh = blockIdx.x & 15, j = 4 + (blockIdx.x >> 4);
    int nsl = 1 + (j >> 2);
    int soff = (j < 8) ? (j - 4) * 2 : (j < 12) ? 8 + (j - 8) * 3 : 20 + (j - 12) * 4;
    int s0 = bh * 36 + soff;
    int tid = threadIdx.x;
    __shared__ float wsum[128];
    if (tid < 128){
        float den = 0.f;
        for (int s = 0; s < nsl; ++s) den += pl[(s0 + s) * 128 + tid];
        wsum[tid] = 1.f / den;
    }
    __syncthreads();
    int b = bh >> 3, h = bh & 7;
    int row = tid >> 1, c0 = (tid & 1) * 64;
    unsigned short* dst = ybf + ((size_t)b * Sn + 128 * j + row) * Dn + h * HDn + c0;
    float W = wsum[row];
    #pragma unroll
    for (int c = 0; c < 8; ++c){
        float o[8] = {0,0,0,0,0,0,0,0};
        for (int s = 0; s < nsl; ++s){
            uint4 v = *(const uint4*)(pab + (size_t)(s0 + s) * 16384 + row * 128 + c0 + c * 8);
            const unsigned short* u = (const unsigned short*)&v;
            #pragma unroll
            for (int e = 0; e < 8; ++e) o[e] += bf2f(u[e]);
        }
        uint4 ov;
        unsigned int* op = (unsigned int*)&ov;
        #pragma unroll
        for (int e = 0; e < 4; ++e) op[e] = pk2(o[2*e] * W, o[2*e+1] * W);
        *(uint4*)(dst + c * 8) = ov;
    }
}

extern "C" void kernel_launch(void* const* d_in, const int* in_sizes, int n_in,
                              void* d_out, int out_size, void* d_ws, size_t ws_size,
                              hipStream_t stream){
    const float* x      = (const float*)d_in[0];
    const float* A      = (const float*)d_in[1];
    const float* Bm     = (const float*)d_in[2];
    const float* C_q    = (const float*)d_in[3];
    const float* C_k    = (const float*)d_in[4];
    const float* C_v    = (const float*)d_in[5];
    const float* C_o    = (const float*)d_in[6];
    const float* C_fc   = (const float*)d_in[7];
    const float* C_proj = (const float*)d_in[8];
    const float* scale1 = (const float*)d_in[9];
    const float* scale2 = (const float*)d_in[10];
    float* out = (float*)d_out;

    char* ws = (char*)d_ws;
    size_t off = 0;
    auto alloc = [&](size_t bytes)->char*{ char* p = ws + off; off += (bytes + 255) & ~(size_t)255; return p; };
    unsigned short* qb   = (unsigned short*)alloc((size_t)Mn * Dn * 2);    // 8MB
    char*           Kimg = alloc((size_t)16 * 32 * 16384);                 // 8MB
    char*           Vimg = alloc((size_t)16 * 32 * 16384);                 // 8MB
    unsigned short* ybf  = (unsigned short*)alloc((size_t)Mn * Dn * 2);    // 8MB
    unsigned short* pab  = (unsigned short*)alloc((size_t)576 * 16384 * 2);// 18.9MB
    float*          pl   = (float*)alloc((size_t)576 * 128 * 4);           // 295KB
    float*          tpA  = (float*)alloc(4 * TSTRIDE * 4);                 // 4MB
    float*          tpB  = (float*)alloc(4 * TSTRIDE * 4);                 // 4MB
    float*          sspA = (float*)alloc(4 * (size_t)Mn * 4);              // 64KB
    float*          sspB = (float*)alloc(4 * (size_t)Mn * 4);              // 64KB
    unsigned short* At0  = (unsigned short*)alloc(65536 * 2);
    unsigned short* At1  = (unsigned short*)alloc(65536 * 2);
    unsigned short* At2  = (unsigned short*)alloc(65536 * 2);
    unsigned short* Btq  = (unsigned short*)alloc(65536 * 2);
    unsigned short* Btk  = (unsigned short*)alloc(65536 * 2);
    unsigned short* Btv  = (unsigned short*)alloc(65536 * 2);
    unsigned short* Bto  = (unsigned short*)alloc(65536 * 2);
    unsigned short* Btfc = (unsigned short*)alloc(65536 * 2);
    unsigned short* Btpr = (unsigned short*)alloc(65536 * 2);
    float2*         rt   = (float2*)alloc((size_t)Sn * 64 * 8);            // 1MB

    prep_g<<<2816, 256, 0, stream>>>(A, Bm, C_q, C_k, C_v, C_o, C_fc, C_proj,
                                     scale1, scale2, At0, At1, At2,
                                     Btq, Btk, Btv, Bto, Btfc, Btpr, rt);
    down_g<0, 1><<<dim3(Mn / 64, 4), 256, 0, stream>>>(x, At1, tpA, sspA);
    qkv_g<<<dim3(Mn / 64, 4), 256, 0, stream>>>(tpA, sspA, Btq, Btk, Btv, rt, qb, Kimg, Vimg);
    attn2_kernel<<<640, 256, 0, stream>>>(qb, Kimg, Vimg, ybf, pab, pl);
    comb_g<<<192, 256, 0, stream>>>(pab, pl, ybf);
    down_g<1, 0><<<dim3(Mn / 64, 4), 256, 0, stream>>>(ybf, At0, tpA, nullptr);
    updown_g<0, 1, 1, 1, 0><<<dim3(Mn / 32, 4), 256, 0, stream>>>(
        tpA, nullptr, Bto, At2, x, out, tpB, sspB);
    updown_g<1, 0, 0, 0, 1><<<dim3(Mn / 32, 4), 256, 0, stream>>>(
        tpB, sspB, Btfc, At0, nullptr, nullptr, tpA, nullptr);
    up_g<0, 1, 0, 0><<<dim3(Mn / 32, 4), 256, 0, stream>>>(tpA, nullptr, Btpr, out, out);
}